// Round 26
// baseline (3470.390 us; speedup 1.0000x reference)
//
#include <hip/hip_runtime.h>
#include <math.h>

typedef unsigned short u16;
typedef __attribute__((ext_vector_type(8))) short bf16x8;
typedef __attribute__((ext_vector_type(4))) float f32x4;

#define MFMA(a, b, c) __builtin_amdgcn_mfma_f32_16x16x32_bf16(a, b, c, 0, 0, 0)

#define Bsz 512
#define Tsz 128
#define Dsz 256
#define CSs 10
#define Hsz 384
#define Gsz 1542
#define HSz 64
#define Gp  1568
#define BG  ((size_t)Bsz * Gp)
#define NGT 98       // Gp/16
#define KTH 12       // 384/32
#define KTX 8        // 256/32
#define KTC 120      // 3840/32

// ---------------- ws layout (byte offsets) ----------------
constexpr size_t O_WPK  = 0;                                   // u16 98*12*2*512
constexpr size_t O_XWPK = O_WPK  + 2ull*NGT*KTH*2*512;         // u16 98*8*2*512
constexpr size_t O_CPK  = O_XWPK + 2ull*NGT*KTX*2*512;         // u16 24*120*512
constexpr size_t O_SPK  = O_CPK  + 2ull*24*KTC*512;            // u16 4*12*2*512
constexpr size_t O_RPK  = O_SPK  + 2ull*4*KTH*2*512;           // u16 24*2*2*512
constexpr size_t O_BC   = O_RPK  + 2ull*24*2*2*512;            // f32 Gp
constexpr size_t O_WT   = O_BC + 4ull*Gp;                      // f32 Gp
constexpr size_t O_HBF  = (O_WT + 4ull*Gp + 255) & ~(size_t)255;  // u16 B*T*H (50 MB)
constexpr size_t O_XPK  = O_HBF + 2ull*Bsz*Tsz*Hsz;            // u16 (67 MB)
constexpr size_t O_XWB  = O_XPK + 2ull*Tsz*32*KTX*2*512;       // f32 2*B*Gp (xw parity)
constexpr size_t O_HWB  = O_XWB + 4ull*2*BG;                   // f32 2*B*Gp (hw parity)
constexpr size_t O_CFB  = O_HWB + 4ull*2*BG;                   // f32 2*B*H (c parity, zeroed)
constexpr size_t ZERO_BEG = O_CFB;
constexpr size_t ZERO_END = O_CFB + 4ull*2*Bsz*Hsz;

__device__ __forceinline__ u16 f2bf(float f) {
    unsigned u = __float_as_uint(f);
    unsigned r = (u + 0x7FFFu + ((u >> 16) & 1u)) >> 16;
    return (u16)r;
}
__device__ __forceinline__ float bf2f(u16 v) {
    return __uint_as_float(((unsigned)v) << 16);
}
__device__ __forceinline__ float sigm(float v) { return 1.f / (1.f + expf(-v)); }

__global__ __launch_bounds__(256) void zero4(float4* __restrict__ p, int n4) {
    int i = blockIdx.x * 256 + threadIdx.x;
    if (i < n4) p[i] = make_float4(0.f, 0.f, 0.f, 0.f);
}

__global__ __launch_bounds__(256) void build_w(const float* __restrict__ kW,
                                               const float* __restrict__ kb,
                                               const float* __restrict__ rW,
                                               const float* __restrict__ rb,
                                               const float* __restrict__ sW,
                                               const float* __restrict__ rsW,
                                               u16* __restrict__ wpk,
                                               u16* __restrict__ xwpk,
                                               u16* __restrict__ spk,
                                               u16* __restrict__ rpk,
                                               float* __restrict__ bc,
                                               float* __restrict__ wt) {
    const int N1 = Gp * 384, N2 = Gp * 256, N3 = 64 * 384, N4 = 384 * 64;
    int idx = blockIdx.x * 256 + threadIdx.x;
    if (idx < N1) {
        int g = idx / 384, k = idx % 384;
        float v = (g < Gsz) ? rW[g * (Hsz + 1) + k] : 0.f;
        u16 hi = f2bf(v), lo = f2bf(v - bf2f(hi));
        size_t fo = ((size_t)((g >> 4) * KTH + (k >> 5)) * 2) * 512;
        int pos = ((g & 15) | (((k >> 3) & 3) << 4)) * 8 + (k & 7);
        wpk[fo + pos] = hi; wpk[fo + 512 + pos] = lo;
    } else if (idx < N1 + N2) {
        int i = idx - N1;
        int g = i / 256, k = i % 256;
        float v = (g < Gsz) ? kW[g * (Dsz + 1) + k] : 0.f;
        u16 hi = f2bf(v), lo = f2bf(v - bf2f(hi));
        size_t fo = ((size_t)((g >> 4) * KTX + (k >> 5)) * 2) * 512;
        int pos = ((g & 15) | (((k >> 3) & 3) << 4)) * 8 + (k & 7);
        xwpk[fo + pos] = hi; xwpk[fo + 512 + pos] = lo;
    } else if (idx < N1 + N2 + N3) {
        int i = idx - N1 - N2;
        int g = i / 384, k = i % 384;              // g<64
        float v = sW[g * Hsz + k];
        u16 hi = f2bf(v), lo = f2bf(v - bf2f(hi));
        size_t fo = ((size_t)((g >> 4) * KTH + (k >> 5)) * 2) * 512;
        int pos = ((g & 15) | (((k >> 3) & 3) << 4)) * 8 + (k & 7);
        spk[fo + pos] = hi; spk[fo + 512 + pos] = lo;
    } else if (idx < N1 + N2 + N3 + N4) {
        int i = idx - N1 - N2 - N3;
        int g = i / 64, k = i % 64;                // g<384
        float v = rsW[g * HSz + k];
        u16 hi = f2bf(v), lo = f2bf(v - bf2f(hi));
        size_t fo = ((size_t)((g >> 4) * 2 + (k >> 5)) * 2) * 512;
        int pos = ((g & 15) | (((k >> 3) & 3) << 4)) * 8 + (k & 7);
        rpk[fo + pos] = hi; rpk[fo + 512 + pos] = lo;
    } else if (idx < N1 + N2 + N3 + N4 + Gsz) {
        int g = idx - N1 - N2 - N3 - N4;
        bc[g] = kb[g] + rb[g];
        wt[g] = kW[g * (Dsz + 1) + Dsz] + rW[g * (Hsz + 1) + Hsz];
    }
}

__global__ __launch_bounds__(256) void pack_x(const float* __restrict__ x,
                                              u16* __restrict__ xpk) {
    int idx = blockIdx.x * 256 + threadIdx.x;
    int k = idx & 255, b = (idx >> 8) & 511, t = idx >> 17;
    float v = x[((size_t)b * Tsz + t) * Dsz + k];
    u16 hi = f2bf(v), lo = f2bf(v - bf2f(hi));
    size_t fo = (((size_t)t * 32 + (b >> 4)) * KTX + (k >> 5)) * 2 * 512;
    int pos = ((b & 15) | (((k >> 3) & 3) << 4)) * 8 + (k & 7);
    xpk[fo + pos] = hi;
    xpk[fo + 512 + pos] = lo;
}

// conv K reordered j-major: k' = j*H + ch (pure permutation)
__global__ __launch_bounds__(256) void pack_cw(const float* __restrict__ cW,
                                               u16* __restrict__ cpk) {
    int idx = blockIdx.x * 256 + threadIdx.x;
    if (idx >= Hsz * Hsz * CSs) return;
    int o = idx / (Hsz * CSs), kk = idx % (Hsz * CSs);
    int ch = kk / CSs, jj = kk % CSs;
    int k2 = jj * Hsz + ch;
    size_t fo = ((size_t)(o >> 4) * KTC + (k2 >> 5)) * 512;
    int pos = ((o & 15) | (((k2 >> 3) & 3) << 4)) * 8 + (k2 & 7);
    cpk[fo + pos] = f2bf(cW[idx]);
}

// ===== fused per-step kernel K(t), t in [0, Tsz] =====
// grid 256 = [mt(32)][sbp(8)], 1024 threads (16 waves), 1 block/CU.
// sbp<7: inline cell(t-1) (768 thr, 8 rows each; sbp==0 writes outputs),
//        h-frags in LDS, then HW tile sbp*14+wave (waves 0..13).
// all sbp: XW tile (base+wave) for slice sbp.
// Parity: xw/hw written at [t&1], read at [(t-1)&1]; cf: c(s) at [s&1].
__global__ __launch_bounds__(1024, 1) void fused(const float* __restrict__ tme,
                                                 char* __restrict__ ws,
                                                 float* __restrict__ out, int t) {
    const u16* wpk  = (const u16*)(ws + O_WPK);
    const u16* xwpk = (const u16*)(ws + O_XWPK);
    const u16* xpk  = (const u16*)(ws + O_XPK);
    const float* bc = (const float*)(ws + O_BC);
    const float* wt = (const float*)(ws + O_WT);
    float* xw = (float*)(ws + O_XWB);
    float* hw = (float*)(ws + O_HWB);
    float* cf = (float*)(ws + O_CFB);
    u16* hbf = (u16*)(ws + O_HBF);
    float* out_seq  = out + (size_t)Bsz * Hsz;
    float* out_dist = out_seq + (size_t)Bsz * Tsz * Hsz;

    int bid = blockIdx.x;
    int tid = threadIdx.x;
    int wave = tid >> 6, lane = tid & 63, l15 = lane & 15, lk = lane >> 4;
    int mt = bid >> 3, sbp = bid & 7;

    __shared__ u16 s_h[KTH][2][512];           // 24,576 B
    __shared__ float s_fi[16][4];

    if (sbp < 7) {
        // ---- cell(t-1) ----
        if (t == 0) {
            for (int i = tid; i < KTH * 2 * 256; i += 1024) ((unsigned*)s_h)[i] = 0u;
        } else {
            const float* xw1 = xw + (size_t)((t - 1) & 1) * BG;
            const float* hw1 = hw + (size_t)((t - 1) & 1) * BG;
            const float* cfo = cf + (size_t)(t & 1) * Bsz * Hsz;        // c(t-2)
            float* cfn = cf + (size_t)((t - 1) & 1) * Bsz * Hsz;        // c(t-1)
            if (tid < 16) {
                int r = tid, b = mt * 16 + r;
                float tv = tme[b * Tsz + (t - 1)];
                const float* xr = xw1 + (size_t)b * Gp;
                const float* hr = hw1 + (size_t)b * Gp;
                float zf[6];
                #pragma unroll
                for (int g = 0; g < 6; ++g)
                    zf[g] = xr[g] + hr[g] + bc[g] + tv * wt[g];
                float m = fmaxf(zf[0], fmaxf(zf[1], zf[2]));
                float e0 = expf(zf[0] - m), e1 = expf(zf[1] - m), e2 = expf(zf[2] - m);
                float inv = 1.f / (e0 + e1 + e2);
                float fm0 = e0 * inv, fm1 = fm0 + e1 * inv;
                float mw = fmaxf(zf[3], fmaxf(zf[4], zf[5]));
                float f0 = expf(zf[3] - mw), f1 = expf(zf[4] - mw), f2 = expf(zf[5] - mw);
                float invw = 1.f / (f0 + f1 + f2);
                float im2 = f2 * invw, im1 = f1 * invw + im2;
                s_fi[r][0] = fm0; s_fi[r][1] = fm1; s_fi[r][2] = im1; s_fi[r][3] = im2;
                if (sbp == 0)
                    out_dist[(size_t)(t - 1) * Bsz + b] = 1.f - (fm0 + fm1 + 1.f) * (1.f / 3.f);
            }
            __syncthreads();
            if (tid < 768) {
                int ch = tid >> 1;
                int rh = tid & 1;          // half: rows rh*8 .. rh*8+7
                int l = ch >> 7;
                int kt = ch >> 5;
                int g0 = 6 + ch, g1 = g0 + Hsz, g2 = g0 + 2 * Hsz, g3 = g0 + 3 * Hsz;
                float bcg0 = bc[g0], bcg1 = bc[g1], bcg2 = bc[g2], bcg3 = bc[g3];
                float wtg0 = wt[g0], wtg1 = wt[g1], wtg2 = wt[g2], wtg3 = wt[g3];
                const float* xr = xw1 + (size_t)(mt * 16 + rh * 8) * Gp;
                const float* hr = hw1 + (size_t)(mt * 16 + rh * 8) * Gp;
                // 2-stage pipeline over 8 rows
                float nx0 = xr[g0], nx1 = xr[g1], nx2 = xr[g2], nx3 = xr[g3];
                float nh0 = hr[g0], nh1 = hr[g1], nh2 = hr[g2], nh3 = hr[g3];
                for (int r2 = 0; r2 < 8; ++r2) {
                    float cx0 = nx0, cx1 = nx1, cx2 = nx2, cx3 = nx3;
                    float hv0 = nh0, hv1 = nh1, hv2 = nh2, hv3 = nh3;
                    if (r2 < 7) {
                        const float* xr2 = xr + (size_t)(r2 + 1) * Gp;
                        const float* hr2 = hr + (size_t)(r2 + 1) * Gp;
                        nx0 = xr2[g0]; nx1 = xr2[g1]; nx2 = xr2[g2]; nx3 = xr2[g3];
                        nh0 = hr2[g0]; nh1 = hr2[g1]; nh2 = hr2[g2]; nh3 = hr2[g3];
                    }
                    int r = rh * 8 + r2;
                    int b = mt * 16 + r;
                    float tv = tme[b * Tsz + (t - 1)];
                    float fm = (l == 0) ? s_fi[r][0] : ((l == 1) ? s_fi[r][1] : 1.f);
                    float im = (l == 0) ? 1.f : ((l == 1) ? s_fi[r][2] : s_fi[r][3]);
                    float fg = sigm(cx0 + hv0 + bcg0 + tv * wtg0);
                    float ig = sigm(cx1 + hv1 + bcg1 + tv * wtg1);
                    float og = sigm(cx2 + hv2 + bcg2 + tv * wtg2);
                    float ci = tanhf(cx3 + hv3 + bcg3 + tv * wtg3);
                    float cl = cfo[(size_t)b * Hsz + ch];
                    float ov = fm * im;
                    float cn = ov * (fg * cl + ig * ci) + (fm - ov) * cl + (im - ov) * ci;
                    float hn = og * tanhf(cn);
                    u16 hh = f2bf(hn);
                    u16 hl = f2bf(hn - bf2f(hh));
                    if (sbp == 0) {
                        cfn[(size_t)b * Hsz + ch] = cn;
                        size_t oi = ((size_t)b * Tsz + (t - 1)) * Hsz + ch;
                        out_seq[oi] = hn;
                        hbf[oi] = hh;
                    }
                    int pos = (r | (((ch >> 3) & 3) << 4)) * 8 + (ch & 7);
                    s_h[kt][0][pos] = hh;
                    s_h[kt][1][pos] = hl;
                }
            }
        }
        __syncthreads();

        // ---- HW(t): wave w (<14) computes tile sbp*14 + w ----
        if (t < Tsz && wave < 14) {
            int gt = sbp * 14 + wave;
            float* dst = hw + (size_t)(t & 1) * BG;
            f32x4 acc = {};
            #pragma unroll
            for (int half = 0; half < 2; ++half) {
                bf16x8 bh[6], bl[6];
                #pragma unroll
                for (int kk = 0; kk < 6; ++kk) {
                    int kt = half * 6 + kk;
                    size_t fb = ((size_t)(gt * KTH + kt) * 2) * 512 + lane * 8;
                    bh[kk] = *(const bf16x8*)(wpk + fb);
                    bl[kk] = *(const bf16x8*)(wpk + fb + 512);
                }
                #pragma unroll
                for (int kk = 0; kk < 6; ++kk) {
                    int kt = half * 6 + kk;
                    bf16x8 ah = *(const bf16x8*)&s_h[kt][0][lane * 8];
                    bf16x8 al = *(const bf16x8*)&s_h[kt][1][lane * 8];
                    acc = MFMA(ah, bh[kk], acc);
                    acc = MFMA(ah, bl[kk], acc);
                    acc = MFMA(al, bh[kk], acc);
                }
            }
            int col = gt * 16 + l15;
            #pragma unroll
            for (int j = 0; j < 4; ++j)
                dst[(size_t)(mt * 16 + lk * 4 + j) * Gp + col] = acc[j];
        }
    }

    // ---- XW(t): wave w computes tile base+w of slice sbp ----
    if (t < Tsz) {
        int base = sbp * 12 + (sbp < 2 ? sbp : 2);
        int cnt  = (sbp < 2) ? 13 : 12;
        if (wave < cnt) {
            int gt = base + wave;
            const u16* Asrc = xpk + ((size_t)(t * 32 + mt) * KTX * 2) * 512;
            bf16x8 ah[KTX], al[KTX];
            #pragma unroll
            for (int kt = 0; kt < KTX; ++kt) {
                ah[kt] = *(const bf16x8*)(Asrc + (size_t)(kt * 2) * 512 + lane * 8);
                al[kt] = *(const bf16x8*)(Asrc + (size_t)(kt * 2 + 1) * 512 + lane * 8);
            }
            float* dst = xw + (size_t)(t & 1) * BG;
            f32x4 acc = {};
            #pragma unroll
            for (int half = 0; half < 2; ++half) {
                bf16x8 bh[4], bl[4];
                #pragma unroll
                for (int kk = 0; kk < 4; ++kk) {
                    int kt = half * 4 + kk;
                    size_t fb = ((size_t)(gt * KTX + kt) * 2) * 512 + lane * 8;
                    bh[kk] = *(const bf16x8*)(xwpk + fb);
                    bl[kk] = *(const bf16x8*)(xwpk + fb + 512);
                }
                #pragma unroll
                for (int kk = 0; kk < 4; ++kk) {
                    int kt = half * 4 + kk;
                    acc = MFMA(ah[kt], bh[kk], acc);
                    acc = MFMA(ah[kt], bl[kk], acc);
                    acc = MFMA(al[kt], bh[kk], acc);
                }
            }
            int col = gt * 16 + l15;
            #pragma unroll
            for (int j = 0; j < 4; ++j)
                dst[(size_t)(mt * 16 + lk * 4 + j) * Gp + col] = acc[j];
        }
    }
}

// ---- phase 2: fully parallel over (b, t). Block = (b, 16 t's). ----
__global__ __launch_bounds__(512, 1) void post(const float* __restrict__ sb,
                                               const float* __restrict__ rsb,
                                               const float* __restrict__ cb,
                                               char* __restrict__ ws,
                                               float* __restrict__ out) {
    const u16* cpk = (const u16*)(ws + O_CPK);
    const u16* spk = (const u16*)(ws + O_SPK);
    const u16* rpk = (const u16*)(ws + O_RPK);
    const u16* hbf = (const u16*)(ws + O_HBF);

    float* out_last = out;
    float* out_seq  = out + (size_t)Bsz * Hsz;
    const float* out_dist = out_seq + (size_t)Bsz * Tsz * Hsz;

    int b = blockIdx.x, t0 = blockIdx.y * 16;
    int tid = threadIdx.x;
    int wave = tid >> 6, lane = tid & 63, l15 = lane & 15, lk = lane >> 4;

    __shared__ u16 s_apk[KTC][512];            // 122,880 B
    __shared__ u16 s_tpk[KTH * 2][512];        // 24,576 B
    __shared__ float th1s[16][68];
    __shared__ float s_ld[16][CSs];

    if (tid < 16) {
        int r = tid;
        float vals[CSs];
        float cum = 0.f;
        #pragma unroll
        for (int j = 0; j < CSs; ++j) {
            int tp = t0 + r - 9 + j;
            float d = (tp < 0) ? 0.f : out_dist[(size_t)tp * Bsz + b];
            cum += d;
            vals[j] = cum;
        }
        float mx = vals[0];
        #pragma unroll
        for (int j = 1; j < CSs; ++j) mx = fmaxf(mx, vals[j]);
        float sum = 0.f;
        #pragma unroll
        for (int j = 0; j < CSs; ++j) { vals[j] = expf(vals[j] - mx); sum += vals[j]; }
        float invs = 1.f / sum;
        #pragma unroll
        for (int j = 0; j < CSs; ++j) s_ld[r][j] = vals[j] * invs;
    }
    __syncthreads();

    // A-build: unit u = c8*16 + r; hbf gathers batched into hv[10] first
    for (int u = tid; u < 768; u += 512) {
        int c8 = u >> 4, r = u & 15;
        int ch0 = c8 * 8;
        int rowoff = c8 >> 2;
        int pos16 = (r | ((c8 & 3) << 4)) * 8;
        bf16x8 hv[CSs];
        #pragma unroll
        for (int j = 0; j < CSs; ++j) {
            int tp = t0 + r - 9 + j;
            bf16x8 z = {};
            hv[j] = (tp >= 0) ? *(const bf16x8*)(hbf + ((size_t)b * Tsz + tp) * Hsz + ch0) : z;
        }
        float acc[8] = {0.f, 0.f, 0.f, 0.f, 0.f, 0.f, 0.f, 0.f};
        #pragma unroll
        for (int j = 0; j < CSs; ++j) {
            float ldv = s_ld[r][j];
            bf16x8 av8;
            #pragma unroll
            for (int e = 0; e < 8; ++e) {
                float av = bf2f((u16)hv[j][e]) * ldv;
                acc[e] += av;
                av8[e] = (short)f2bf(av);
            }
            *(bf16x8*)&s_apk[j * 12 + rowoff][pos16] = av8;
        }
        bf16x8 th8, tl8;
        #pragma unroll
        for (int e = 0; e < 8; ++e) {
            float thm = acc[e] * 0.1f;
            u16 th = f2bf(thm);
            th8[e] = (short)th;
            tl8[e] = (short)f2bf(thm - bf2f(th));
        }
        int kt2 = rowoff * 2;
        *(bf16x8*)&s_tpk[kt2][pos16] = th8;
        *(bf16x8*)&s_tpk[kt2 + 1][pos16] = tl8;
    }
    __syncthreads();

    // conv MFMA: deepest batch (24 kt x 3 ot = 72 loads nominal) + theme stage 1
    f32x4 cacc[3] = {};
    for (int k0 = 0; k0 < KTC; k0 += 24) {
        bf16x8 bv[3][24];
        #pragma unroll
        for (int kk = 0; kk < 24; ++kk)
            #pragma unroll
            for (int i = 0; i < 3; ++i)
                bv[i][kk] = *(const bf16x8*)(cpk + ((size_t)((wave * 3 + i) * KTC + k0 + kk)) * 512 + lane * 8);
        #pragma unroll
        for (int kk = 0; kk < 24; ++kk) {
            bf16x8 a = *(const bf16x8*)&s_apk[k0 + kk][lane * 8];
            #pragma unroll
            for (int i = 0; i < 3; ++i)
                cacc[i] = MFMA(a, bv[i][kk], cacc[i]);
        }
    }
    if (wave < 4) {
        // batch all 24 spk loads before the MFMA chain
        bf16x8 sbh[KTH], sbl[KTH];
        #pragma unroll
        for (int kt = 0; kt < KTH; ++kt) {
            size_t bb = ((size_t)(wave * KTH + kt) * 2) * 512 + lane * 8;
            sbh[kt] = *(const bf16x8*)(spk + bb);
            sbl[kt] = *(const bf16x8*)(spk + bb + 512);
        }
        f32x4 a1 = {};
        #pragma unroll
        for (int kt = 0; kt < KTH; ++kt) {
            bf16x8 ah = *(const bf16x8*)&s_tpk[kt * 2][lane * 8];
            bf16x8 al = *(const bf16x8*)&s_tpk[kt * 2 + 1][lane * 8];
            a1 = MFMA(ah, sbh[kt], a1);
            a1 = MFMA(ah, sbl[kt], a1);
            a1 = MFMA(al, sbh[kt], a1);
        }
        int col = wave * 16 + l15;
        #pragma unroll
        for (int j = 0; j < 4; ++j)
            th1s[lk * 4 + j][col] = fmaxf(a1[j] + sb[col], 0.f);
    }
    __syncthreads();

    // theme stage 2 + epilogue: out = sigm(mlp)*(conv+cb) + h
    bf16x8 ah2[2], al2[2];
    #pragma unroll
    for (int kt = 0; kt < 2; ++kt) {
        bf16x8 zh, zl;
        #pragma unroll
        for (int e = 0; e < 8; ++e) {
            float v = th1s[l15][kt * 32 + lk * 8 + e];
            u16 hi = f2bf(v);
            zh[e] = (short)hi;
            zl[e] = (short)f2bf(v - bf2f(hi));
        }
        ah2[kt] = zh; al2[kt] = zl;
    }
    #pragma unroll
    for (int i = 0; i < 3; ++i) {
        int ot = wave * 3 + i;
        f32x4 a2 = {};
        #pragma unroll
        for (int kt = 0; kt < 2; ++kt) {
            size_t bb = ((size_t)(ot * 2 + kt) * 2) * 512 + lane * 8;
            bf16x8 bh = *(const bf16x8*)(rpk + bb);
            bf16x8 bl = *(const bf16x8*)(rpk + bb + 512);
            a2 = MFMA(ah2[kt], bh, a2);
            a2 = MFMA(ah2[kt], bl, a2);
            a2 = MFMA(al2[kt], bh, a2);
        }
        int col = ot * 16 + l15;
        #pragma unroll
        for (int j = 0; j < 4; ++j) {
            int row = lk * 4 + j;
            int tt = t0 + row;
            size_t oi = ((size_t)b * Tsz + tt) * Hsz + col;
            float convv = cacc[i][j] + cb[col];
            float th = sigm(a2[j] + rsb[col]);
            float val = th * convv + out_seq[oi];
            out_seq[oi] = val;
            if (tt == Tsz - 1) out_last[(size_t)b * Hsz + col] = val;
        }
    }
}

extern "C" void kernel_launch(void* const* d_in, const int* in_sizes, int n_in,
                              void* d_out, int out_size, void* d_ws, size_t ws_size,
                              hipStream_t stream) {
    const float* x   = (const float*)d_in[0];
    const float* tme = (const float*)d_in[1];
    const float* kW  = (const float*)d_in[2];
    const float* kb  = (const float*)d_in[3];
    const float* rW  = (const float*)d_in[4];
    const float* rb  = (const float*)d_in[5];
    const float* sW  = (const float*)d_in[6];
    const float* sb  = (const float*)d_in[7];
    const float* rsW = (const float*)d_in[8];
    const float* rsb = (const float*)d_in[9];
    const float* cW  = (const float*)d_in[10];
    const float* cb  = (const float*)d_in[11];

    char* wsb = (char*)d_ws;
    float* outp = (float*)d_out;

    u16* wpk  = (u16*)(wsb + O_WPK);
    u16* xwpk = (u16*)(wsb + O_XWPK);
    u16* cpk  = (u16*)(wsb + O_CPK);
    u16* spk  = (u16*)(wsb + O_SPK);
    u16* rpk  = (u16*)(wsb + O_RPK);
    float* bc = (float*)(wsb + O_BC);
    float* wt = (float*)(wsb + O_WT);
    u16* xpk  = (u16*)(wsb + O_XPK);

    zero4<<<(int)((ZERO_END - ZERO_BEG) / 16 + 255) / 256, 256, 0, stream>>>(
        (float4*)(wsb + ZERO_BEG), (int)((ZERO_END - ZERO_BEG) / 16));
    {
        int nW = Gp * 384 + Gp * 256 + 64 * 384 + 384 * 64 + Gsz;
        build_w<<<(nW + 255) / 256, 256, 0, stream>>>(kW, kb, rW, rb, sW, rsW,
                                                      wpk, xwpk, spk, rpk, bc, wt);
    }
    pack_x<<<(Tsz * Bsz * Dsz) / 256, 256, 0, stream>>>(x, xpk);
    pack_cw<<<(Hsz * Hsz * CSs + 255) / 256, 256, 0, stream>>>(cW, cpk);

    for (int t = 0; t <= Tsz; ++t)
        fused<<<256, 1024, 0, stream>>>(tme, wsb, outp, t);
    post<<<dim3(Bsz, Tsz / 16), 512, 0, stream>>>(sb, rsb, cb, wsb, outp);
}

// Round 27
// 3462.131 us; speedup vs baseline: 1.0024x; 1.0024x over previous
//
#include <hip/hip_runtime.h>
#include <math.h>

typedef unsigned short u16;
typedef __attribute__((ext_vector_type(8))) short bf16x8;
typedef __attribute__((ext_vector_type(4))) float f32x4;

#define MFMA(a, b, c) __builtin_amdgcn_mfma_f32_16x16x32_bf16(a, b, c, 0, 0, 0)

#define Bsz 512
#define Tsz 128
#define Dsz 256
#define CSs 10
#define Hsz 384
#define Gsz 1542
#define HSz 64
#define Gp  1568
#define BG  ((size_t)Bsz * Gp)
#define NGT 98       // Gp/16
#define KTH 12       // 384/32
#define KTX 8        // 256/32
#define KTC 120      // 3840/32

// ---------------- ws layout (byte offsets) ----------------
constexpr size_t O_WPK  = 0;                                   // u16 98*12*2*512
constexpr size_t O_XWPK = O_WPK  + 2ull*NGT*KTH*2*512;         // u16 98*8*2*512
constexpr size_t O_CPK  = O_XWPK + 2ull*NGT*KTX*2*512;         // u16 24*120*512
constexpr size_t O_SPK  = O_CPK  + 2ull*24*KTC*512;            // u16 4*12*2*512
constexpr size_t O_RPK  = O_SPK  + 2ull*4*KTH*2*512;           // u16 24*2*2*512
constexpr size_t O_BC   = O_RPK  + 2ull*24*2*2*512;            // f32 Gp
constexpr size_t O_WT   = O_BC + 4ull*Gp;                      // f32 Gp
constexpr size_t O_HBF  = (O_WT + 4ull*Gp + 255) & ~(size_t)255;  // u16 B*T*H (50 MB)
constexpr size_t O_XPK  = O_HBF + 2ull*Bsz*Tsz*Hsz;            // u16 (67 MB)
constexpr size_t O_XWB  = O_XPK + 2ull*Tsz*32*KTX*2*512;       // f32 2*B*Gp (xw parity)
constexpr size_t O_HWB  = O_XWB + 4ull*2*BG;                   // f32 2*B*Gp (hw parity)
constexpr size_t O_CFB  = O_HWB + 4ull*2*BG;                   // f32 2*B*H (c parity, zeroed)
constexpr size_t ZERO_BEG = O_CFB;
constexpr size_t ZERO_END = O_CFB + 4ull*2*Bsz*Hsz;

__device__ __forceinline__ u16 f2bf(float f) {
    unsigned u = __float_as_uint(f);
    unsigned r = (u + 0x7FFFu + ((u >> 16) & 1u)) >> 16;
    return (u16)r;
}
__device__ __forceinline__ float bf2f(u16 v) {
    return __uint_as_float(((unsigned)v) << 16);
}
__device__ __forceinline__ float sigm(float v) { return 1.f / (1.f + expf(-v)); }

__global__ __launch_bounds__(256) void zero4(float4* __restrict__ p, int n4) {
    int i = blockIdx.x * 256 + threadIdx.x;
    if (i < n4) p[i] = make_float4(0.f, 0.f, 0.f, 0.f);
}

__global__ __launch_bounds__(256) void build_w(const float* __restrict__ kW,
                                               const float* __restrict__ kb,
                                               const float* __restrict__ rW,
                                               const float* __restrict__ rb,
                                               const float* __restrict__ sW,
                                               const float* __restrict__ rsW,
                                               u16* __restrict__ wpk,
                                               u16* __restrict__ xwpk,
                                               u16* __restrict__ spk,
                                               u16* __restrict__ rpk,
                                               float* __restrict__ bc,
                                               float* __restrict__ wt) {
    const int N1 = Gp * 384, N2 = Gp * 256, N3 = 64 * 384, N4 = 384 * 64;
    int idx = blockIdx.x * 256 + threadIdx.x;
    if (idx < N1) {
        int g = idx / 384, k = idx % 384;
        float v = (g < Gsz) ? rW[g * (Hsz + 1) + k] : 0.f;
        u16 hi = f2bf(v), lo = f2bf(v - bf2f(hi));
        size_t fo = ((size_t)((g >> 4) * KTH + (k >> 5)) * 2) * 512;
        int pos = ((g & 15) | (((k >> 3) & 3) << 4)) * 8 + (k & 7);
        wpk[fo + pos] = hi; wpk[fo + 512 + pos] = lo;
    } else if (idx < N1 + N2) {
        int i = idx - N1;
        int g = i / 256, k = i % 256;
        float v = (g < Gsz) ? kW[g * (Dsz + 1) + k] : 0.f;
        u16 hi = f2bf(v), lo = f2bf(v - bf2f(hi));
        size_t fo = ((size_t)((g >> 4) * KTX + (k >> 5)) * 2) * 512;
        int pos = ((g & 15) | (((k >> 3) & 3) << 4)) * 8 + (k & 7);
        xwpk[fo + pos] = hi; xwpk[fo + 512 + pos] = lo;
    } else if (idx < N1 + N2 + N3) {
        int i = idx - N1 - N2;
        int g = i / 384, k = i % 384;              // g<64
        float v = sW[g * Hsz + k];
        u16 hi = f2bf(v), lo = f2bf(v - bf2f(hi));
        size_t fo = ((size_t)((g >> 4) * KTH + (k >> 5)) * 2) * 512;
        int pos = ((g & 15) | (((k >> 3) & 3) << 4)) * 8 + (k & 7);
        spk[fo + pos] = hi; spk[fo + 512 + pos] = lo;
    } else if (idx < N1 + N2 + N3 + N4) {
        int i = idx - N1 - N2 - N3;
        int g = i / 64, k = i % 64;                // g<384
        float v = rsW[g * HSz + k];
        u16 hi = f2bf(v), lo = f2bf(v - bf2f(hi));
        size_t fo = ((size_t)((g >> 4) * 2 + (k >> 5)) * 2) * 512;
        int pos = ((g & 15) | (((k >> 3) & 3) << 4)) * 8 + (k & 7);
        rpk[fo + pos] = hi; rpk[fo + 512 + pos] = lo;
    } else if (idx < N1 + N2 + N3 + N4 + Gsz) {
        int g = idx - N1 - N2 - N3 - N4;
        bc[g] = kb[g] + rb[g];
        wt[g] = kW[g * (Dsz + 1) + Dsz] + rW[g * (Hsz + 1) + Hsz];
    }
}

__global__ __launch_bounds__(256) void pack_x(const float* __restrict__ x,
                                              u16* __restrict__ xpk) {
    int idx = blockIdx.x * 256 + threadIdx.x;
    int k = idx & 255, b = (idx >> 8) & 511, t = idx >> 17;
    float v = x[((size_t)b * Tsz + t) * Dsz + k];
    u16 hi = f2bf(v), lo = f2bf(v - bf2f(hi));
    size_t fo = (((size_t)t * 32 + (b >> 4)) * KTX + (k >> 5)) * 2 * 512;
    int pos = ((b & 15) | (((k >> 3) & 3) << 4)) * 8 + (k & 7);
    xpk[fo + pos] = hi;
    xpk[fo + 512 + pos] = lo;
}

// conv K reordered j-major: k' = j*H + ch (pure permutation)
__global__ __launch_bounds__(256) void pack_cw(const float* __restrict__ cW,
                                               u16* __restrict__ cpk) {
    int idx = blockIdx.x * 256 + threadIdx.x;
    if (idx >= Hsz * Hsz * CSs) return;
    int o = idx / (Hsz * CSs), kk = idx % (Hsz * CSs);
    int ch = kk / CSs, jj = kk % CSs;
    int k2 = jj * Hsz + ch;
    size_t fo = ((size_t)(o >> 4) * KTC + (k2 >> 5)) * 512;
    int pos = ((o & 15) | (((k2 >> 3) & 3) << 4)) * 8 + (k2 & 7);
    cpk[fo + pos] = f2bf(cW[idx]);
}

// ===== fused per-step kernel K(t), t in [0, Tsz] =====
// grid 256 = [mt(32)][sbp(8)], 1024 threads (16 waves), 1 block/CU.
// sbp<7: inline cell(t-1) (768 thr, 8 rows each; sbp==0 writes outputs),
//        h-frags in LDS, then HW tile sbp*14+wave (waves 0..13).
// all sbp: XW tile (base+wave) for slice sbp.
// Parity: xw/hw written at [t&1], read at [(t-1)&1]; cf: c(s) at [s&1].
__global__ __launch_bounds__(1024, 1) void fused(const float* __restrict__ tme,
                                                 char* __restrict__ ws,
                                                 float* __restrict__ out, int t) {
    const u16* wpk  = (const u16*)(ws + O_WPK);
    const u16* xwpk = (const u16*)(ws + O_XWPK);
    const u16* xpk  = (const u16*)(ws + O_XPK);
    const float* bc = (const float*)(ws + O_BC);
    const float* wt = (const float*)(ws + O_WT);
    float* xw = (float*)(ws + O_XWB);
    float* hw = (float*)(ws + O_HWB);
    float* cf = (float*)(ws + O_CFB);
    u16* hbf = (u16*)(ws + O_HBF);
    float* out_seq  = out + (size_t)Bsz * Hsz;
    float* out_dist = out_seq + (size_t)Bsz * Tsz * Hsz;

    int bid = blockIdx.x;
    int tid = threadIdx.x;
    int wave = tid >> 6, lane = tid & 63, l15 = lane & 15, lk = lane >> 4;
    int mt = bid >> 3, sbp = bid & 7;

    __shared__ u16 s_h[KTH][2][512];           // 24,576 B
    __shared__ float s_fi[16][4];

    if (sbp < 7) {
        // ---- cell(t-1) ----
        if (t == 0) {
            for (int i = tid; i < KTH * 2 * 256; i += 1024) ((unsigned*)s_h)[i] = 0u;
        } else {
            const float* xw1 = xw + (size_t)((t - 1) & 1) * BG;
            const float* hw1 = hw + (size_t)((t - 1) & 1) * BG;
            const float* cfo = cf + (size_t)(t & 1) * Bsz * Hsz;        // c(t-2)
            float* cfn = cf + (size_t)((t - 1) & 1) * Bsz * Hsz;        // c(t-1)
            if (tid < 16) {
                int r = tid, b = mt * 16 + r;
                float tv = tme[b * Tsz + (t - 1)];
                const float* xr = xw1 + (size_t)b * Gp;
                const float* hr = hw1 + (size_t)b * Gp;
                float zf[6];
                #pragma unroll
                for (int g = 0; g < 6; ++g)
                    zf[g] = xr[g] + hr[g] + bc[g] + tv * wt[g];
                float m = fmaxf(zf[0], fmaxf(zf[1], zf[2]));
                float e0 = expf(zf[0] - m), e1 = expf(zf[1] - m), e2 = expf(zf[2] - m);
                float inv = 1.f / (e0 + e1 + e2);
                float fm0 = e0 * inv, fm1 = fm0 + e1 * inv;
                float mw = fmaxf(zf[3], fmaxf(zf[4], zf[5]));
                float f0 = expf(zf[3] - mw), f1 = expf(zf[4] - mw), f2 = expf(zf[5] - mw);
                float invw = 1.f / (f0 + f1 + f2);
                float im2 = f2 * invw, im1 = f1 * invw + im2;
                s_fi[r][0] = fm0; s_fi[r][1] = fm1; s_fi[r][2] = im1; s_fi[r][3] = im2;
                if (sbp == 0)
                    out_dist[(size_t)(t - 1) * Bsz + b] = 1.f - (fm0 + fm1 + 1.f) * (1.f / 3.f);
            }
            __syncthreads();
            if (tid < 768) {
                int ch = tid >> 1;
                int rh = tid & 1;          // half: rows rh*8 .. rh*8+7
                int l = ch >> 7;
                int kt = ch >> 5;
                int g0 = 6 + ch, g1 = g0 + Hsz, g2 = g0 + 2 * Hsz, g3 = g0 + 3 * Hsz;
                float bcg0 = bc[g0], bcg1 = bc[g1], bcg2 = bc[g2], bcg3 = bc[g3];
                float wtg0 = wt[g0], wtg1 = wt[g1], wtg2 = wt[g2], wtg3 = wt[g3];
                const float* xr = xw1 + (size_t)(mt * 16 + rh * 8) * Gp;
                const float* hr = hw1 + (size_t)(mt * 16 + rh * 8) * Gp;
                // 2-stage pipeline over 8 rows
                float nx0 = xr[g0], nx1 = xr[g1], nx2 = xr[g2], nx3 = xr[g3];
                float nh0 = hr[g0], nh1 = hr[g1], nh2 = hr[g2], nh3 = hr[g3];
                for (int r2 = 0; r2 < 8; ++r2) {
                    float cx0 = nx0, cx1 = nx1, cx2 = nx2, cx3 = nx3;
                    float hv0 = nh0, hv1 = nh1, hv2 = nh2, hv3 = nh3;
                    if (r2 < 7) {
                        const float* xr2 = xr + (size_t)(r2 + 1) * Gp;
                        const float* hr2 = hr + (size_t)(r2 + 1) * Gp;
                        nx0 = xr2[g0]; nx1 = xr2[g1]; nx2 = xr2[g2]; nx3 = xr2[g3];
                        nh0 = hr2[g0]; nh1 = hr2[g1]; nh2 = hr2[g2]; nh3 = hr2[g3];
                    }
                    int r = rh * 8 + r2;
                    int b = mt * 16 + r;
                    float tv = tme[b * Tsz + (t - 1)];
                    float fm = (l == 0) ? s_fi[r][0] : ((l == 1) ? s_fi[r][1] : 1.f);
                    float im = (l == 0) ? 1.f : ((l == 1) ? s_fi[r][2] : s_fi[r][3]);
                    float fg = sigm(cx0 + hv0 + bcg0 + tv * wtg0);
                    float ig = sigm(cx1 + hv1 + bcg1 + tv * wtg1);
                    float og = sigm(cx2 + hv2 + bcg2 + tv * wtg2);
                    float ci = tanhf(cx3 + hv3 + bcg3 + tv * wtg3);
                    float cl = cfo[(size_t)b * Hsz + ch];
                    float ov = fm * im;
                    float cn = ov * (fg * cl + ig * ci) + (fm - ov) * cl + (im - ov) * ci;
                    float hn = og * tanhf(cn);
                    u16 hh = f2bf(hn);
                    u16 hl = f2bf(hn - bf2f(hh));
                    if (sbp == 0) {
                        cfn[(size_t)b * Hsz + ch] = cn;
                        size_t oi = ((size_t)b * Tsz + (t - 1)) * Hsz + ch;
                        out_seq[oi] = hn;
                        hbf[oi] = hh;
                    }
                    int pos = (r | (((ch >> 3) & 3) << 4)) * 8 + (ch & 7);
                    s_h[kt][0][pos] = hh;
                    s_h[kt][1][pos] = hl;
                }
            }
        }
        __syncthreads();

        // ---- HW(t): wave w (<14) computes tile sbp*14 + w ----
        if (t < Tsz && wave < 14) {
            int gt = sbp * 14 + wave;
            float* dst = hw + (size_t)(t & 1) * BG;
            f32x4 acc = {};
            #pragma unroll
            for (int half = 0; half < 2; ++half) {
                bf16x8 bh[6], bl[6];
                #pragma unroll
                for (int kk = 0; kk < 6; ++kk) {
                    int kt = half * 6 + kk;
                    size_t fb = ((size_t)(gt * KTH + kt) * 2) * 512 + lane * 8;
                    bh[kk] = *(const bf16x8*)(wpk + fb);
                    bl[kk] = *(const bf16x8*)(wpk + fb + 512);
                }
                #pragma unroll
                for (int kk = 0; kk < 6; ++kk) {
                    int kt = half * 6 + kk;
                    bf16x8 ah = *(const bf16x8*)&s_h[kt][0][lane * 8];
                    bf16x8 al = *(const bf16x8*)&s_h[kt][1][lane * 8];
                    acc = MFMA(ah, bh[kk], acc);
                    acc = MFMA(ah, bl[kk], acc);
                    acc = MFMA(al, bh[kk], acc);
                }
            }
            int col = gt * 16 + l15;
            #pragma unroll
            for (int j = 0; j < 4; ++j)
                dst[(size_t)(mt * 16 + lk * 4 + j) * Gp + col] = acc[j];
        }
    }

    // ---- XW(t): wave w computes tile base+w of slice sbp ----
    if (t < Tsz) {
        int base = sbp * 12 + (sbp < 2 ? sbp : 2);
        int cnt  = (sbp < 2) ? 13 : 12;
        if (wave < cnt) {
            int gt = base + wave;
            const u16* Asrc = xpk + ((size_t)(t * 32 + mt) * KTX * 2) * 512;
            bf16x8 ah[KTX], al[KTX];
            #pragma unroll
            for (int kt = 0; kt < KTX; ++kt) {
                ah[kt] = *(const bf16x8*)(Asrc + (size_t)(kt * 2) * 512 + lane * 8);
                al[kt] = *(const bf16x8*)(Asrc + (size_t)(kt * 2 + 1) * 512 + lane * 8);
            }
            float* dst = xw + (size_t)(t & 1) * BG;
            f32x4 acc = {};
            #pragma unroll
            for (int half = 0; half < 2; ++half) {
                bf16x8 bh[4], bl[4];
                #pragma unroll
                for (int kk = 0; kk < 4; ++kk) {
                    int kt = half * 4 + kk;
                    size_t fb = ((size_t)(gt * KTX + kt) * 2) * 512 + lane * 8;
                    bh[kk] = *(const bf16x8*)(xwpk + fb);
                    bl[kk] = *(const bf16x8*)(xwpk + fb + 512);
                }
                #pragma unroll
                for (int kk = 0; kk < 4; ++kk) {
                    int kt = half * 4 + kk;
                    acc = MFMA(ah[kt], bh[kk], acc);
                    acc = MFMA(ah[kt], bl[kk], acc);
                    acc = MFMA(al[kt], bh[kk], acc);
                }
            }
            int col = gt * 16 + l15;
            #pragma unroll
            for (int j = 0; j < 4; ++j)
                dst[(size_t)(mt * 16 + lk * 4 + j) * Gp + col] = acc[j];
        }
    }
}

// ---- phase 2: fully parallel over (b, t). Block = (b, 16 t's). ----
__global__ __launch_bounds__(512, 1) void post(const float* __restrict__ sb,
                                               const float* __restrict__ rsb,
                                               const float* __restrict__ cb,
                                               char* __restrict__ ws,
                                               float* __restrict__ out) {
    const u16* cpk = (const u16*)(ws + O_CPK);
    const u16* spk = (const u16*)(ws + O_SPK);
    const u16* rpk = (const u16*)(ws + O_RPK);
    const u16* hbf = (const u16*)(ws + O_HBF);

    float* out_last = out;
    float* out_seq  = out + (size_t)Bsz * Hsz;
    const float* out_dist = out_seq + (size_t)Bsz * Tsz * Hsz;

    int b = blockIdx.x, t0 = blockIdx.y * 16;
    int tid = threadIdx.x;
    int wave = tid >> 6, lane = tid & 63, l15 = lane & 15, lk = lane >> 4;

    __shared__ u16 s_apk[KTC][512];            // 122,880 B
    __shared__ u16 s_tpk[KTH * 2][512];        // 24,576 B
    __shared__ float th1s[16][68];
    __shared__ float s_ld[16][CSs];

    if (tid < 16) {
        int r = tid;
        float vals[CSs];
        float cum = 0.f;
        #pragma unroll
        for (int j = 0; j < CSs; ++j) {
            int tp = t0 + r - 9 + j;
            float d = (tp < 0) ? 0.f : out_dist[(size_t)tp * Bsz + b];
            cum += d;
            vals[j] = cum;
        }
        float mx = vals[0];
        #pragma unroll
        for (int j = 1; j < CSs; ++j) mx = fmaxf(mx, vals[j]);
        float sum = 0.f;
        #pragma unroll
        for (int j = 0; j < CSs; ++j) { vals[j] = expf(vals[j] - mx); sum += vals[j]; }
        float invs = 1.f / sum;
        #pragma unroll
        for (int j = 0; j < CSs; ++j) s_ld[r][j] = vals[j] * invs;
    }
    __syncthreads();

    // A-build: unit u = c8*16 + r; hbf gathers batched into hv[10] first
    for (int u = tid; u < 768; u += 512) {
        int c8 = u >> 4, r = u & 15;
        int ch0 = c8 * 8;
        int rowoff = c8 >> 2;
        int pos16 = (r | ((c8 & 3) << 4)) * 8;
        bf16x8 hv[CSs];
        #pragma unroll
        for (int j = 0; j < CSs; ++j) {
            int tp = t0 + r - 9 + j;
            bf16x8 z = {};
            hv[j] = (tp >= 0) ? *(const bf16x8*)(hbf + ((size_t)b * Tsz + tp) * Hsz + ch0) : z;
        }
        float acc[8] = {0.f, 0.f, 0.f, 0.f, 0.f, 0.f, 0.f, 0.f};
        #pragma unroll
        for (int j = 0; j < CSs; ++j) {
            float ldv = s_ld[r][j];
            bf16x8 av8;
            #pragma unroll
            for (int e = 0; e < 8; ++e) {
                float av = bf2f((u16)hv[j][e]) * ldv;
                acc[e] += av;
                av8[e] = (short)f2bf(av);
            }
            *(bf16x8*)&s_apk[j * 12 + rowoff][pos16] = av8;
        }
        bf16x8 th8, tl8;
        #pragma unroll
        for (int e = 0; e < 8; ++e) {
            float thm = acc[e] * 0.1f;
            u16 th = f2bf(thm);
            th8[e] = (short)th;
            tl8[e] = (short)f2bf(thm - bf2f(th));
        }
        int kt2 = rowoff * 2;
        *(bf16x8*)&s_tpk[kt2][pos16] = th8;
        *(bf16x8*)&s_tpk[kt2 + 1][pos16] = tl8;
    }
    __syncthreads();

    // conv MFMA: batch depth 15 (45 loads in flight) + theme stage 1
    f32x4 cacc[3] = {};
    for (int k0 = 0; k0 < KTC; k0 += 15) {
        bf16x8 bv[3][15];
        #pragma unroll
        for (int kk = 0; kk < 15; ++kk)
            #pragma unroll
            for (int i = 0; i < 3; ++i)
                bv[i][kk] = *(const bf16x8*)(cpk + ((size_t)((wave * 3 + i) * KTC + k0 + kk)) * 512 + lane * 8);
        #pragma unroll
        for (int kk = 0; kk < 15; ++kk) {
            bf16x8 a = *(const bf16x8*)&s_apk[k0 + kk][lane * 8];
            #pragma unroll
            for (int i = 0; i < 3; ++i)
                cacc[i] = MFMA(a, bv[i][kk], cacc[i]);
        }
    }
    if (wave < 4) {
        f32x4 a1 = {};
        for (int kt = 0; kt < KTH; ++kt) {
            bf16x8 ah = *(const bf16x8*)&s_tpk[kt * 2][lane * 8];
            bf16x8 al = *(const bf16x8*)&s_tpk[kt * 2 + 1][lane * 8];
            size_t bb = ((size_t)(wave * KTH + kt) * 2) * 512 + lane * 8;
            bf16x8 bh = *(const bf16x8*)(spk + bb);
            bf16x8 bl = *(const bf16x8*)(spk + bb + 512);
            a1 = MFMA(ah, bh, a1);
            a1 = MFMA(ah, bl, a1);
            a1 = MFMA(al, bh, a1);
        }
        int col = wave * 16 + l15;
        #pragma unroll
        for (int j = 0; j < 4; ++j)
            th1s[lk * 4 + j][col] = fmaxf(a1[j] + sb[col], 0.f);
    }
    __syncthreads();

    // theme stage 2 + epilogue: out = sigm(mlp)*(conv+cb) + h
    bf16x8 ah2[2], al2[2];
    #pragma unroll
    for (int kt = 0; kt < 2; ++kt) {
        bf16x8 zh, zl;
        #pragma unroll
        for (int e = 0; e < 8; ++e) {
            float v = th1s[l15][kt * 32 + lk * 8 + e];
            u16 hi = f2bf(v);
            zh[e] = (short)hi;
            zl[e] = (short)f2bf(v - bf2f(hi));
        }
        ah2[kt] = zh; al2[kt] = zl;
    }
    #pragma unroll
    for (int i = 0; i < 3; ++i) {
        int ot = wave * 3 + i;
        f32x4 a2 = {};
        #pragma unroll
        for (int kt = 0; kt < 2; ++kt) {
            size_t bb = ((size_t)(ot * 2 + kt) * 2) * 512 + lane * 8;
            bf16x8 bh = *(const bf16x8*)(rpk + bb);
            bf16x8 bl = *(const bf16x8*)(rpk + bb + 512);
            a2 = MFMA(ah2[kt], bh, a2);
            a2 = MFMA(ah2[kt], bl, a2);
            a2 = MFMA(al2[kt], bh, a2);
        }
        int col = ot * 16 + l15;
        #pragma unroll
        for (int j = 0; j < 4; ++j) {
            int row = lk * 4 + j;
            int tt = t0 + row;
            size_t oi = ((size_t)b * Tsz + tt) * Hsz + col;
            float convv = cacc[i][j] + cb[col];
            float th = sigm(a2[j] + rsb[col]);
            float val = th * convv + out_seq[oi];
            out_seq[oi] = val;
            if (tt == Tsz - 1) out_last[(size_t)b * Hsz + col] = val;
        }
    }
}

extern "C" void kernel_launch(void* const* d_in, const int* in_sizes, int n_in,
                              void* d_out, int out_size, void* d_ws, size_t ws_size,
                              hipStream_t stream) {
    const float* x   = (const float*)d_in[0];
    const float* tme = (const float*)d_in[1];
    const float* kW  = (const float*)d_in[2];
    const float* kb  = (const float*)d_in[3];
    const float* rW  = (const float*)d_in[4];
    const float* rb  = (const float*)d_in[5];
    const float* sW  = (const float*)d_in[6];
    const float* sb  = (const float*)d_in[7];
    const float* rsW = (const float*)d_in[8];
    const float* rsb = (const float*)d_in[9];
    const float* cW  = (const float*)d_in[10];
    const float* cb  = (const float*)d_in[11];

    char* wsb = (char*)d_ws;
    float* outp = (float*)d_out;

    u16* wpk  = (u16*)(wsb + O_WPK);
    u16* xwpk = (u16*)(wsb + O_XWPK);
    u16* cpk  = (u16*)(wsb + O_CPK);
    u16* spk  = (u16*)(wsb + O_SPK);
    u16* rpk  = (u16*)(wsb + O_RPK);
    float* bc = (float*)(wsb + O_BC);
    float* wt = (float*)(wsb + O_WT);
    u16* xpk  = (u16*)(wsb + O_XPK);

    zero4<<<(int)((ZERO_END - ZERO_BEG) / 16 + 255) / 256, 256, 0, stream>>>(
        (float4*)(wsb + ZERO_BEG), (int)((ZERO_END - ZERO_BEG) / 16));
    {
        int nW = Gp * 384 + Gp * 256 + 64 * 384 + 384 * 64 + Gsz;
        build_w<<<(nW + 255) / 256, 256, 0, stream>>>(kW, kb, rW, rb, sW, rsW,
                                                      wpk, xwpk, spk, rpk, bc, wt);
    }
    pack_x<<<(Tsz * Bsz * Dsz) / 256, 256, 0, stream>>>(x, xpk);
    pack_cw<<<(Hsz * Hsz * CSs + 255) / 256, 256, 0, stream>>>(cW, cpk);

    for (int t = 0; t <= Tsz; ++t)
        fused<<<256, 1024, 0, stream>>>(tme, wsb, outp, t);
    post<<<dim3(Bsz, Tsz / 16), 512, 0, stream>>>(sb, rsb, cb, wsb, outp);
}